// Round 1
// 2390.643 us; speedup vs baseline: 1.0741x; 1.0741x over previous
//
#include <hip/hip_runtime.h>
#include <stdint.h>

typedef unsigned short u16;
typedef __bf16 bf16_t;
typedef bf16_t bf16x8 __attribute__((ext_vector_type(8)));
typedef float f32x4 __attribute__((ext_vector_type(4)));

// ---------- helpers ----------
static __device__ __forceinline__ u16 f2bf(float f) {
  union { float f; uint32_t u; } cv; cv.f = f;
  uint32_t u = cv.u;
  return (u16)((u + 0x7FFFu + ((u >> 16) & 1u)) >> 16);
}

static __device__ __forceinline__ void gload16(const void* g, void* l) {
  __builtin_amdgcn_global_load_lds(
      (__attribute__((address_space(1))) void*)g,
      (__attribute__((address_space(3))) void*)l, 16, 0, 0);
}

// ---------- embed: x = tok_emb[idx] + pos_emb ----------
__global__ __launch_bounds__(256) void embed_kernel(const int* __restrict__ idx,
                                                    const float* __restrict__ tok,
                                                    const float* __restrict__ pos,
                                                    float* __restrict__ x) {
  int row = blockIdx.x, tid = threadIdx.x;
  int t = row & 511;
  int v = idx[row];
  float4 a = ((const float4*)(tok + (long)v * 1024))[tid];
  float4 p = ((const float4*)(pos + (long)t * 1024))[tid];
  a.x += p.x; a.y += p.y; a.z += p.z; a.w += p.w;
  ((float4*)(x + (long)row * 1024))[tid] = a;
}

// ---------- layernorm (fp32 in -> bf16 out), one block per row, C=1024 ----------
__global__ __launch_bounds__(256) void ln_kernel(const float* __restrict__ in,
                                                 const float* __restrict__ g,
                                                 const float* __restrict__ b,
                                                 u16* __restrict__ out) {
  int row = blockIdx.x, tid = threadIdx.x;
  int wid = tid >> 6, lane = tid & 63;
  const float4 v = ((const float4*)(in + (long)row * 1024))[tid];
  float s1 = v.x + v.y + v.z + v.w;
  float s2 = v.x*v.x + v.y*v.y + v.z*v.z + v.w*v.w;
#pragma unroll
  for (int o = 32; o >= 1; o >>= 1) { s1 += __shfl_xor(s1, o); s2 += __shfl_xor(s2, o); }
  __shared__ float red1[4], red2[4];
  if (lane == 0) { red1[wid] = s1; red2[wid] = s2; }
  __syncthreads();
  s1 = red1[0] + red1[1] + red1[2] + red1[3];
  s2 = red2[0] + red2[1] + red2[2] + red2[3];
  float mu = s1 * (1.f/1024.f);
  float var = s2 * (1.f/1024.f) - mu*mu;
  float rstd = rsqrtf(var + 1e-5f);
  const float4 gg = ((const float4*)g)[tid];
  const float4 bb = ((const float4*)b)[tid];
  ushort4 o4;
  o4.x = f2bf((v.x - mu)*rstd*gg.x + bb.x);
  o4.y = f2bf((v.y - mu)*rstd*gg.y + bb.y);
  o4.z = f2bf((v.z - mu)*rstd*gg.z + bb.z);
  o4.w = f2bf((v.w - mu)*rstd*gg.w + bb.w);
  ((ushort4*)(out + (long)row * 1024))[tid] = o4;
}

// ---------- fp32 -> bf16 cast ----------
__global__ __launch_bounds__(256) void cast_kernel(const float* __restrict__ src,
                                                   u16* __restrict__ dst, int n4) {
  int i = blockIdx.x * 256 + threadIdx.x;
  if (i >= n4) return;
  float4 v = ((const float4*)src)[i];
  ushort4 o; o.x = f2bf(v.x); o.y = f2bf(v.y); o.z = f2bf(v.z); o.w = f2bf(v.w);
  ((ushort4*)dst)[i] = o;
}

// per-layer fused cast of wqkv(3C*C), wp(C*C), w1(4C*C), w2(C*4C); grid = 12288
__global__ __launch_bounds__(256) void cast4_kernel(const float* __restrict__ s0,
                                                    const float* __restrict__ s1,
                                                    const float* __restrict__ s2,
                                                    const float* __restrict__ s3,
                                                    u16* __restrict__ d0, u16* __restrict__ d1,
                                                    u16* __restrict__ d2, u16* __restrict__ d3) {
  int i = blockIdx.x * 256 + threadIdx.x;  // group-of-4 index, total 3145728
  const float* s; u16* d; int off;
  if (i < 786432)       { s = s0; d = d0; off = i; }
  else if (i < 1048576) { s = s1; d = d1; off = i - 786432; }
  else if (i < 2097152) { s = s2; d = d2; off = i - 1048576; }
  else                  { s = s3; d = d3; off = i - 2097152; }
  float4 v = ((const float4*)s)[off];
  ushort4 o; o.x = f2bf(v.x); o.y = f2bf(v.y); o.z = f2bf(v.z); o.w = f2bf(v.w);
  ((ushort4*)d)[off] = o;
}

// ---------- causal softmax over S rows (fp32 in, bf16 P out), T=512 ----------
__global__ __launch_bounds__(256) void softmax_kernel(const float* __restrict__ S,
                                                      u16* __restrict__ P) {
  int wid = threadIdx.x >> 6, lane = threadIdx.x & 63;
  long R = (long)blockIdx.x * 4 + wid;    // bh*512 + q
  int q = (int)(R & 511);
  const float* row = S + R * 512;
  float v[8];
  float m = -3.4e38f;
#pragma unroll
  for (int j = 0; j < 8; ++j) {
    int t = j*64 + lane;
    v[j] = (t <= q) ? row[t] : -3.4e38f;
    m = fmaxf(m, v[j]);
  }
#pragma unroll
  for (int o = 32; o >= 1; o >>= 1) m = fmaxf(m, __shfl_xor(m, o));
  float s = 0.f;
#pragma unroll
  for (int j = 0; j < 8; ++j) {
    int t = j*64 + lane;
    v[j] = (t <= q) ? __expf(v[j] - m) : 0.f;
    s += v[j];
  }
#pragma unroll
  for (int o = 32; o >= 1; o >>= 1) s += __shfl_xor(s, o);
  float inv = 1.f / s;
  u16* prow = P + R * 512;
#pragma unroll
  for (int j = 0; j < 8; ++j) prow[j*64 + lane] = f2bf(v[j] * inv);
}

// ---------- NT GEMM: C[M,N] = A[M,K](bf16) * B[N,K](bf16)^T, fp32 accum ----------
// BM=128 fixed, BK=32. 4 waves in 2x2, wave tile 64 x (BN/2).
// XSWAP: m0 comes from blockIdx.x (fast dim) so the M-blocks sharing one
//        B panel dispatch consecutively -> B panel stays hot in L2/L3.
// Epilogues: 0=f32*scale  1=bf16 (with z->(b,h) split strides)  2=f32 residual-add
//            3=GELU->bf16  4=QKV scatter (Q,K [bh][t][d], Vt [bh][d][t])
enum { EPI_F32 = 0, EPI_BF16 = 1, EPI_RES = 2, EPI_GELU = 3, EPI_QKV = 4 };

template<int BN, int EPI, bool CSKIP, bool CKLIM, bool XSWAP>
__global__ __launch_bounds__(256, 2) void gemm_nt(
    const u16* __restrict__ A, const u16* __restrict__ Bw,
    float* __restrict__ Cf, u16* __restrict__ Cb, const float* __restrict__ Res,
    int K, int ldc, float scale,
    long sAz, long sBz, long sCb, long sCh, int Hdiv,
    u16* __restrict__ q_out, u16* __restrict__ k_out, u16* __restrict__ vt_out) {
  constexpr int BM = 128, BK = 32;
  __shared__ __align__(16) u16 As[BM * BK];
  __shared__ __align__(16) u16 Bs[BN * BK];
  const int tid = threadIdx.x;
  const int wid = tid >> 6, lane = tid & 63;
  const int n0 = (XSWAP ? blockIdx.y : blockIdx.x) * BN;
  const int m0 = (XSWAP ? blockIdx.x : blockIdx.y) * BM;
  const long z = blockIdx.z;
  if (CSKIP && n0 > m0) return;          // causal: skip strictly-upper tiles
  const u16* Ab = A + z * sAz;
  const u16* Bb = Bw + z * sBz;
  int kend = K;
  if (CKLIM) { int ke = m0 + BM; kend = ke < K ? ke : K; }

  const int wm = wid & 1, wn = wid >> 1;
  constexpr int NF = BN / 32;            // n-frags per wave (4 or 2)
  constexpr int BPW = BN / 64;           // B staging chunks per wave (2 or 1)
  f32x4 acc[4][NF];
  f32x4 zero = {0.f, 0.f, 0.f, 0.f};
#pragma unroll
  for (int i = 0; i < 4; ++i)
#pragma unroll
    for (int j = 0; j < NF; ++j) acc[i][j] = zero;

  // precompute staging addresses (f = chunk*64 + lane; 16B per lane)
  const int fA0 = (wid * 2) * 64 + lane, fA1 = fA0 + 64;
  const u16* gA0 = Ab + (long)(m0 + (fA0 >> 2)) * K + ((fA0 & 3) << 3);
  const u16* gA1 = Ab + (long)(m0 + (fA1 >> 2)) * K + ((fA1 & 3) << 3);
  u16* lA0 = &As[(wid * 2) * 512];
  u16* lA1 = lA0 + 512;
  const u16* gB[BPW]; u16* lB[BPW];
#pragma unroll
  for (int i = 0; i < BPW; ++i) {
    int f = (wid * BPW + i) * 64 + lane;
    gB[i] = Bb + (long)(n0 + (f >> 2)) * K + ((f & 3) << 3);
    lB[i] = &Bs[(wid * BPW + i) * 512];
  }
  const int lm = lane & 15, lq = lane >> 4;

  for (int k0 = 0; k0 < kend; k0 += BK) {
    __syncthreads();
    gload16(gA0 + k0, lA0);
    gload16(gA1 + k0, lA1);
#pragma unroll
    for (int i = 0; i < BPW; ++i) gload16(gB[i] + k0, lB[i]);
    __syncthreads();
    bf16x8 af[4], bfr[NF];
#pragma unroll
    for (int i = 0; i < 4; ++i)
      af[i] = *(const bf16x8*)&As[(wm * 64 + i * 16 + lm) * BK + lq * 8];
#pragma unroll
    for (int j = 0; j < NF; ++j)
      bfr[j] = *(const bf16x8*)&Bs[(wn * (BN / 2) + j * 16 + lm) * BK + lq * 8];
#pragma unroll
    for (int i = 0; i < 4; ++i)
#pragma unroll
      for (int j = 0; j < NF; ++j)
        acc[i][j] = __builtin_amdgcn_mfma_f32_16x16x32_bf16(af[i], bfr[j], acc[i][j], 0, 0, 0);
  }

  const long coff = (z / Hdiv) * sCb + (z % Hdiv) * sCh;
#pragma unroll
  for (int i = 0; i < 4; ++i) {
#pragma unroll
    for (int j = 0; j < NF; ++j) {
#pragma unroll
      for (int r = 0; r < 4; ++r) {
        int row = m0 + wm * 64 + i * 16 + lq * 4 + r;
        int col = n0 + wn * (BN / 2) + j * 16 + lm;
        float v = acc[i][j][r];
        if (EPI == EPI_F32) {
          Cf[coff + (long)row * ldc + col] = v * scale;
        } else if (EPI == EPI_BF16) {
          Cb[coff + (long)row * ldc + col] = f2bf(v);
        } else if (EPI == EPI_RES) {
          long idx = (long)row * ldc + col;
          Cf[idx] = Res[idx] + v;
        } else if (EPI == EPI_GELU) {
          float gl = 0.5f * v * (1.0f + erff(v * 0.70710678118654752f));
          Cb[(long)row * ldc + col] = f2bf(gl);
        } else {  // EPI_QKV
          int which = col >> 10, wc = col & 1023;
          int hh = wc >> 6, d = wc & 63;
          int bb2 = row >> 9, t = row & 511;
          long bh = bb2 * 16 + hh;
          u16 val = f2bf(v);
          if (which == 0)      q_out[(bh * 512 + t) * 64 + d] = val;
          else if (which == 1) k_out[(bh * 512 + t) * 64 + d] = val;
          else                 vt_out[(bh * 64 + d) * 512 + t] = val;
        }
      }
    }
  }
}

// ---------- launch ----------
extern "C" void kernel_launch(void* const* d_in, const int* in_sizes, int n_in,
                              void* d_out, int out_size, void* d_ws, size_t ws_size,
                              hipStream_t stream) {
  (void)in_sizes; (void)n_in; (void)out_size; (void)ws_size;
  const int*   idx   = (const int*)  d_in[0];
  const float* tok   = (const float*)d_in[1];
  const float* pos   = (const float*)d_in[2];
  const float* ln1g  = (const float*)d_in[3];
  const float* ln1b  = (const float*)d_in[4];
  const float* attnw = (const float*)d_in[5];
  const float* projw = (const float*)d_in[6];
  const float* ln2g  = (const float*)d_in[7];
  const float* ln2b  = (const float*)d_in[8];
  const float* w1w   = (const float*)d_in[9];
  const float* w2w   = (const float*)d_in[10];
  const float* lnfg  = (const float*)d_in[11];
  const float* lnfb  = (const float*)d_in[12];
  const float* headw = (const float*)d_in[13];

  // scratch inside d_out (262 MB; only the final head GEMM writes logits, which
  // overwrites all of this after the last read of any region below)
  char* ob = (char*)d_out;
  float* Sf  = (float*)(ob + 0);            // [64][512][512] f32   67,108,864
  u16*   Pb  = (u16*)  (ob + 67108864);     // [64][512][512] bf16  33,554,432
  u16*   m1b = (u16*)  (ob + 100663296);    // [2048][4096]  bf16   16,777,216
  u16*   Qb  = (u16*)  (ob + 117440512);    // [64][512][64] bf16    4,194,304
  u16*   Kb  = (u16*)  (ob + 121634816);    // [64][512][64] bf16    4,194,304
  u16*   Vtb = (u16*)  (ob + 125829120);    // [64][64][512] bf16    4,194,304
  u16*   yb  = (u16*)  (ob + 130023424);    // [2048][1024]  bf16    4,194,304
  float* ab  = (float*)(ob + 134217728);    // [2048][1024]  f32     8,388,608
  float* xb  = (float*)(ob + 142606336);    // [2048][1024]  f32     8,388,608

  // ws: only things live during the head GEMM
  char* wsb = (char*)d_ws;
  u16* hb    = (u16*)(wsb + 0);             //  4,194,304
  u16* wqkvb = (u16*)(wsb + 4194304);       //  6,291,456
  u16* wpb   = (u16*)(wsb + 10485760);      //  2,097,152
  u16* w1b   = (u16*)(wsb + 12582912);      //  8,388,608
  u16* w2b   = (u16*)(wsb + 20971520);      //  8,388,608
  u16* headb = (u16*)(wsb + 29360128);      // 65,536,000  (total 94,896,128)

  embed_kernel<<<2048, 256, 0, stream>>>(idx, tok, pos, xb);

  for (int l = 0; l < 8; ++l) {
    cast4_kernel<<<12288, 256, 0, stream>>>(
        attnw + (size_t)l * 3145728, projw + (size_t)l * 1048576,
        w1w + (size_t)l * 4194304,   w2w + (size_t)l * 4194304,
        wqkvb, wpb, w1b, w2b);
    ln_kernel<<<2048, 256, 0, stream>>>(xb, ln1g + l * 1024, ln1b + l * 1024, hb);
    // qkv = h @ wqkv^T, scatter to Q,K,Vt  (M fast-dim: 16 M-blocks share B panel)
    gemm_nt<128, EPI_QKV, false, false, true><<<dim3(16, 24, 1), 256, 0, stream>>>(
        hb, wqkvb, nullptr, nullptr, nullptr, 1024, 0, 1.f,
        0, 0, 0, 0, 1, Qb, Kb, Vtb);
    // S = (Q K^T) * 0.125, batched over bh, skip upper-causal tiles
    gemm_nt<128, EPI_F32, true, false, false><<<dim3(4, 4, 64), 256, 0, stream>>>(
        Qb, Kb, Sf, nullptr, nullptr, 64, 512, 0.125f,
        32768, 32768, 262144, 0, 1, nullptr, nullptr, nullptr);
    softmax_kernel<<<8192, 256, 0, stream>>>(Sf, Pb);
    // y = P @ Vt^T  (store as [b][t][h*64+d]), K-loop limited by causality
    gemm_nt<64, EPI_BF16, false, true, false><<<dim3(1, 4, 64), 256, 0, stream>>>(
        Pb, Vtb, nullptr, yb, nullptr, 512, 1024, 1.f,
        262144, 32768, 524288, 64, 16, nullptr, nullptr, nullptr);
    // a = x + y @ wp^T   (BN=64 -> 256 blocks so all CUs are occupied)
    gemm_nt<64, EPI_RES, false, false, true><<<dim3(16, 16, 1), 256, 0, stream>>>(
        yb, wpb, ab, nullptr, xb, 1024, 1024, 1.f,
        0, 0, 0, 0, 1, nullptr, nullptr, nullptr);
    ln_kernel<<<2048, 256, 0, stream>>>(ab, ln2g + l * 1024, ln2b + l * 1024, hb);
    // m1 = gelu(h2 @ w1^T)
    gemm_nt<128, EPI_GELU, false, false, true><<<dim3(16, 32, 1), 256, 0, stream>>>(
        hb, w1b, nullptr, m1b, nullptr, 1024, 4096, 1.f,
        0, 0, 0, 0, 1, nullptr, nullptr, nullptr);
    // x = x + m1 @ w2^T   (BN=64 -> 256 blocks; outer residual adds x, NOT a)
    gemm_nt<64, EPI_RES, false, false, true><<<dim3(16, 16, 1), 256, 0, stream>>>(
        m1b, w2b, xb, nullptr, xb, 4096, 1024, 1.f,
        0, 0, 0, 0, 1, nullptr, nullptr, nullptr);
  }

  ln_kernel<<<2048, 256, 0, stream>>>(xb, lnfg, lnfb, hb);
  cast_kernel<<<32000, 256, 0, stream>>>(headw, headb, 8192000);
  // logits = lnf_h @ head_w^T  -> d_out (fp32), overwrites all scratch regions
  // M fast-dim: one 256KB B panel is reused by 16 consecutive blocks before
  // the 262MB C-write stream can evict it from L2/L3.
  gemm_nt<128, EPI_F32, false, false, true><<<dim3(16, 250, 1), 256, 0, stream>>>(
      hb, headb, (float*)d_out, nullptr, nullptr, 1024, 32000, 1.f,
      0, 0, 0, 0, 1, nullptr, nullptr, nullptr);
}